// Round 13
// baseline (706.511 us; speedup 1.0000x reference)
//
#include <hip/hip_runtime.h>

// ---------------------------------------------------------------------------
// GemNet InteractionBlock forward, MI355X (gfx950).
// Round 13: res_layer kernels (front/chain/asi) moved to 256-thread / 64-row
// / 32KB-LDS blocks, launch_bounds(256,5) -> 5 blocks/CU. Per-wave geometry
// identical to r12. Bilinear (v8) and atom chain unchanged.
// ---------------------------------------------------------------------------

#define EE 120000
#define NA 10000

constexpr float C_INV = 0.70710678118654752440f;

using f32x4 = __attribute__((ext_vector_type(4))) float;
using f32x2 = __attribute__((ext_vector_type(2))) float;
using s16x8 = __attribute__((ext_vector_type(8))) short;
using s16x4 = __attribute__((ext_vector_type(4))) short;

__device__ __forceinline__ float act_silu(float x) { return x / (1.0f + __expf(-x)); }

__device__ __forceinline__ unsigned short f2bf(float f) {
    unsigned int u = __float_as_uint(f);
    u += 0x7fffu + ((u >> 16) & 1u);
    return (unsigned short)(u >> 16);
}
__device__ __forceinline__ float bf2f(unsigned short h) {
    return __uint_as_float(((unsigned int)h) << 16);
}
__device__ __forceinline__ unsigned int cvtpk(float a, float b) {
    unsigned int r;
    asm("v_cvt_pk_bf16_f32 %0, %1, %2" : "=v"(r) : "v"(a), "v"(b));
    return r;
}

// ---------------------------------------------------------------------------
// weight fragment preload + MFMA with preloaded weights (b from swizzled LDS)
// ---------------------------------------------------------------------------
template<int MT, int KQ>
__device__ __forceinline__ void load_w(const unsigned short* __restrict__ W, int KW,
                                       int l, s16x8 (&a)[MT][KQ])
{
    const int fr = l & 15;
    const int k8 = (l >> 4) << 3;
    #pragma unroll
    for (int mt = 0; mt < MT; ++mt)
        #pragma unroll
        for (int kq = 0; kq < KQ; ++kq)
            a[mt][kq] = *(const s16x8*)&W[(size_t)(mt * 16 + fr) * KW + kq * 32 + k8];
}

template<int MT, int NF, int KQ>
__device__ __forceinline__ void gemm_pre(
    const s16x8 (&a)[MT][KQ], const char* ldsB, int RS,
    int rowBase, int l, f32x4 (&acc)[MT][NF])
{
    const int fr = l & 15;
    const int k8 = (l >> 4) << 3;
    #pragma unroll
    for (int kq = 0; kq < KQ; ++kq) {
        s16x8 b[NF];
        #pragma unroll
        for (int nf = 0; nf < NF; ++nf) {
            const int row = rowBase + nf * 16 + fr;
            const int kb  = ((kq * 32 + k8) * 2) ^ ((row & 7) << 4);
            b[nf] = *(const s16x8*)(ldsB + row * RS + kb);
        }
        #pragma unroll
        for (int mt = 0; mt < MT; ++mt)
            #pragma unroll
            for (int nf = 0; nf < NF; ++nf)
                acc[mt][nf] = __builtin_amdgcn_mfma_f32_16x16x32_bf16(
                    a[mt][kq], b[nf], acc[mt][nf], 0, 0, 0);
    }
}

template<int MT, int NF>
__device__ __forceinline__ void zacc(f32x4 (&acc)[MT][NF])
{
    #pragma unroll
    for (int mt = 0; mt < MT; ++mt)
        #pragma unroll
        for (int nf = 0; nf < NF; ++nf)
            acc[mt][nf] = (f32x4){0.f, 0.f, 0.f, 0.f};
}

__device__ __forceinline__ void packA(char* lds, int RS, int row, int outF0, f32x4 v)
{
    uint2 p;
    p.x = cvtpk(v[0], v[1]);
    p.y = cvtpk(v[2], v[3]);
    *(uint2*)(lds + row * RS + ((outF0 * 2) ^ ((row & 7) << 4))) = p;
}

__device__ __forceinline__ void store_bf4(unsigned short* dst, f32x4 v)
{
    uint2 p;
    p.x = cvtpk(v[0], v[1]);
    p.y = cvtpk(v[2], v[3]);
    *(uint2*)dst = p;
}

// stage ROWS x 128 f32 -> swizzled bf16 LDS (RS=256), T threads
template<int ROWS, int T>
__device__ __forceinline__ void stage_f32(char* lds, const float* __restrict__ src,
                                          int row0, int M, int tid)
{
    #pragma unroll
    for (int u = 0; u < ROWS * 16 / T; ++u) {
        const int flat = tid + u * T;
        const int row  = flat >> 4;
        const int k8   = (flat & 15) << 3;
        const int grow = row0 + row;
        uint4 val = {0u, 0u, 0u, 0u};
        if (grow < M) {
            const float* p = src + (size_t)grow * 128 + k8;
            f32x4 lo = *(const f32x4*)p;
            f32x4 hi = *(const f32x4*)(p + 4);
            val.x = cvtpk(lo[0], lo[1]);
            val.y = cvtpk(lo[2], lo[3]);
            val.z = cvtpk(hi[0], hi[1]);
            val.w = cvtpk(hi[2], hi[3]);
        }
        *(uint4*)(lds + row * 256 + ((k8 * 2) ^ ((row & 7) << 4))) = val;
    }
}

// ---------------------------------------------------------------------------
// one ResidualLayer: waves own feature-quarters (wm), rows = wn*NF*16 .. +NF*16
// ---------------------------------------------------------------------------
template<bool MSTM, int NF>
__device__ __forceinline__ void res_layer(
    char* A, char* B,
    const unsigned short* W0, const unsigned short* W1,
    int wm, int wn, int l, f32x4 (&x)[2][NF],
    const s16x4 (*ms)[NF])
{
    const int fr = l & 15;
    const int fq = (l >> 4) << 2;

    s16x8 aw[2][4];
    load_w<2, 4>(W0 + (size_t)(wm * 32) * 128, 128, l, aw);
    f32x4 acc[2][NF];
    zacc(acc);
    gemm_pre<2, NF, 4>(aw, A, 256, wn * NF * 16, l, acc);

    s16x8 aw1[2][4];
    load_w<2, 4>(W1 + (size_t)(wm * 32) * 128, 128, l, aw1);   // issue before barrier

    #pragma unroll
    for (int mt = 0; mt < 2; ++mt)
        #pragma unroll
        for (int nf = 0; nf < NF; ++nf) {
            const int row = wn * NF * 16 + nf * 16 + fr;
            const int of0 = wm * 32 + mt * 16 + fq;
            f32x4 v;
            #pragma unroll
            for (int q = 0; q < 4; ++q) v[q] = act_silu(acc[mt][nf][q]);
            packA(B, 256, row, of0, v);
        }
    __syncthreads();

    zacc(acc);
    gemm_pre<2, NF, 4>(aw1, B, 256, wn * NF * 16, l, acc);
    #pragma unroll
    for (int mt = 0; mt < 2; ++mt)
        #pragma unroll
        for (int nf = 0; nf < NF; ++nf) {
            const int row = wn * NF * 16 + nf * 16 + fr;
            const int of0 = wm * 32 + mt * 16 + fq;
            #pragma unroll
            for (int q = 0; q < 4; ++q)
                x[mt][nf][q] = (x[mt][nf][q] + act_silu(acc[mt][nf][q])) * C_INV;
            if (MSTM) {
                #pragma unroll
                for (int q = 0; q < 4; ++q)
                    x[mt][nf][q] = (x[mt][nf][q] +
                                    bf2f((unsigned short)ms[mt][nf][q])) * C_INV;
            }
            packA(A, 256, row, of0, x[mt][nf]);
        }
    __syncthreads();
}

__device__ __forceinline__ s16x4 read_frag(const char* lds, int row, int of0)
{
    return *(const s16x4*)(lds + row * 256 + ((of0 * 2) ^ ((row & 7) << 4)));
}

// ---------------------------------------------------------------------------
// front (256 thr, 64-row): tpre = act(m_st@W_m_kt)*scale ; mkt = act(tpre@W_down)
// ---------------------------------------------------------------------------
__global__ __launch_bounds__(256, 5) void front_k(
    const float* __restrict__ m_st, const unsigned short* __restrict__ scale_b,
    const unsigned short* __restrict__ Wmkt, const unsigned short* __restrict__ Wdown,
    unsigned short* __restrict__ mkt_b)
{
    __shared__ char A[64 * 256];
    const int tid = threadIdx.x;
    const int l = tid & 63, wm = tid >> 6;
    const int fr = l & 15, fq = (l >> 4) << 2;
    const int row0 = blockIdx.x * 64;

    s16x8 aw[2][4];
    load_w<2, 4>(Wmkt + (size_t)(wm * 32) * 128, 128, l, aw);

    stage_f32<64, 256>(A, m_st, row0, EE, tid);
    __syncthreads();

    f32x4 acc[2][4];
    zacc(acc);
    gemm_pre<2, 4, 4>(aw, A, 256, 0, l, acc);

    s16x8 aw2[1][4];
    load_w<1, 4>(Wdown + (size_t)(wm * 16) * 128, 128, l, aw2);

    __syncthreads();
    #pragma unroll
    for (int mt = 0; mt < 2; ++mt)
        #pragma unroll
        for (int nf = 0; nf < 4; ++nf) {
            const int row = nf * 16 + fr;
            const int grow = row0 + row;
            const int of0 = wm * 32 + mt * 16 + fq;
            f32x4 v = {0.f, 0.f, 0.f, 0.f};
            if (grow < EE) {
                s16x4 sc = *(const s16x4*)&scale_b[(size_t)grow * 128 + of0];
                #pragma unroll
                for (int q = 0; q < 4; ++q)
                    v[q] = act_silu(acc[mt][nf][q]) * bf2f((unsigned short)sc[q]);
            }
            packA(A, 256, row, of0, v);
        }
    __syncthreads();

    f32x4 acc2[1][4];
    zacc(acc2);
    gemm_pre<1, 4, 4>(aw2, A, 256, 0, l, acc2);
    #pragma unroll
    for (int nf = 0; nf < 4; ++nf) {
        const int row = nf * 16 + fr;
        const int grow = row0 + row;
        if (grow >= EE) continue;
        const int of0 = wm * 16 + fq;
        f32x4 v;
        #pragma unroll
        for (int q = 0; q < 4; ++q) v[q] = act_silu(acc2[0][nf][q]);
        store_bf4(&mkt_b[(size_t)grow * 64 + of0], v);
    }
}

// ---------------------------------------------------------------------------
// chain (256 thr, 64-row): x_skip + merge + resb + m_st merge + resa x2
// ---------------------------------------------------------------------------
__global__ __launch_bounds__(256, 5) void chain_k(
    const float* __restrict__ m_st,
    const unsigned short* __restrict__ yst, const unsigned short* __restrict__ yts,
    const int* __restrict__ idx_swap,
    const unsigned short* __restrict__ Wmlp,
    const unsigned short* __restrict__ Wrb0, const unsigned short* __restrict__ Wrb1,
    const unsigned short* __restrict__ Wra0, const unsigned short* __restrict__ Wra1,
    const unsigned short* __restrict__ Wra2, const unsigned short* __restrict__ Wra3,
    unsigned short* __restrict__ xb_out)
{
    __shared__ char A[64 * 256];
    __shared__ char B[64 * 256];
    const int tid = threadIdx.x;
    const int l = tid & 63, wm = tid >> 6;
    const int fr = l & 15, fq = (l >> 4) << 2;
    const int row0 = blockIdx.x * 64;

    s16x8 aw[2][4];
    load_w<2, 4>(Wmlp + (size_t)(wm * 32) * 128, 128, l, aw);

    stage_f32<64, 256>(A, m_st, row0, EE, tid);
    __syncthreads();

    f32x4 acc[2][4];
    zacc(acc);
    gemm_pre<2, 4, 4>(aw, A, 256, 0, l, acc);

    s16x4 ms[2][4];
    #pragma unroll
    for (int mt = 0; mt < 2; ++mt)
        #pragma unroll
        for (int nf = 0; nf < 4; ++nf)
            ms[mt][nf] = read_frag(A, nf * 16 + fr, wm * 32 + mt * 16 + fq);

    f32x4 x[2][4];
    #pragma unroll
    for (int mt = 0; mt < 2; ++mt)
        #pragma unroll
        for (int nf = 0; nf < 4; ++nf) {
            const int row = nf * 16 + fr;
            const int grow = row0 + row;
            const int of0 = wm * 32 + mt * 16 + fq;
            if (grow < EE) {
                s16x4 a = *(const s16x4*)&yst[(size_t)grow * 128 + of0];
                const int sw = idx_swap[grow];
                s16x4 b = *(const s16x4*)&yts[(size_t)sw * 128 + of0];
                #pragma unroll
                for (int q = 0; q < 4; ++q)
                    x[mt][nf][q] = (acc[mt][nf][q] +
                        (bf2f((unsigned short)a[q]) + bf2f((unsigned short)b[q])) * C_INV) * C_INV;
            } else {
                x[mt][nf] = (f32x4){0.f, 0.f, 0.f, 0.f};
            }
        }
    __syncthreads();
    #pragma unroll
    for (int mt = 0; mt < 2; ++mt)
        #pragma unroll
        for (int nf = 0; nf < 4; ++nf)
            packA(A, 256, nf * 16 + fr, wm * 32 + mt * 16 + fq, x[mt][nf]);
    __syncthreads();

    res_layer<true , 4>(A, B, Wrb0, Wrb1, wm, 0, l, x, ms);
    res_layer<false, 4>(A, B, Wra0, Wra1, wm, 0, l, x, nullptr);
    res_layer<false, 4>(A, B, Wra2, Wra3, wm, 0, l, x, nullptr);

    #pragma unroll
    for (int mt = 0; mt < 2; ++mt)
        #pragma unroll
        for (int nf = 0; nf < 4; ++nf) {
            const int row = nf * 16 + fr;
            const int grow = row0 + row;
            if (grow >= EE) continue;
            const int of0 = wm * 32 + mt * 16 + fq;
            store_bf4(&xb_out[(size_t)grow * 128 + of0], x[mt][nf]);
        }
}

// ---------------------------------------------------------------------------
// atom chain (512 thr, 64-row tiles, NF=2) - unchanged (tiny grid)
// ---------------------------------------------------------------------------
__global__ __launch_bounds__(512, 4) void atom_k(
    const float* __restrict__ h2,
    const unsigned short* __restrict__ Wae,
    const unsigned short* __restrict__ Wr0, const unsigned short* __restrict__ Wr1,
    const unsigned short* __restrict__ Wr2, const unsigned short* __restrict__ Wr3,
    float* __restrict__ out_h, unsigned short* __restrict__ h_b)
{
    __shared__ char A[64 * 256];
    __shared__ char B[64 * 256];
    const int tid = threadIdx.x;
    const int l = tid & 63, w = tid >> 6, wm = w & 3, wn = w >> 2;
    const int fr = l & 15, fq = (l >> 4) << 2;
    const int row0 = blockIdx.x * 64;

    s16x8 aw[2][4];
    load_w<2, 4>(Wae + (size_t)(wm * 32) * 128, 128, l, aw);

    stage_f32<64, 512>(A, h2, row0, NA, tid);
    __syncthreads();

    f32x4 acc[2][2];
    zacc(acc);
    gemm_pre<2, 2, 4>(aw, A, 256, wn * 32, l, acc);
    f32x4 x[2][2];
    #pragma unroll
    for (int mt = 0; mt < 2; ++mt)
        #pragma unroll
        for (int nf = 0; nf < 2; ++nf)
            #pragma unroll
            for (int q = 0; q < 4; ++q)
                x[mt][nf][q] = act_silu(acc[mt][nf][q]);
    __syncthreads();
    #pragma unroll
    for (int mt = 0; mt < 2; ++mt)
        #pragma unroll
        for (int nf = 0; nf < 2; ++nf)
            packA(A, 256, wn * 32 + nf * 16 + fr, wm * 32 + mt * 16 + fq, x[mt][nf]);
    __syncthreads();

    res_layer<false, 2>(A, B, Wr0, Wr1, wm, wn, l, x, nullptr);
    res_layer<false, 2>(A, B, Wr2, Wr3, wm, wn, l, x, nullptr);

    #pragma unroll
    for (int mt = 0; mt < 2; ++mt)
        #pragma unroll
        for (int nf = 0; nf < 2; ++nf) {
            const int row = wn * 32 + nf * 16 + fr;
            const int grow = row0 + row;
            if (grow >= NA) continue;
            const int of0 = wm * 32 + mt * 16 + fq;
            *(f32x4*)&out_h[(size_t)grow * 128 + of0] = x[mt][nf];
            store_bf4(&h_b[(size_t)grow * 128 + of0], x[mt][nf]);
        }
}

// ---------------------------------------------------------------------------
// ASI + res_m (256 thr, 64-row)
// ---------------------------------------------------------------------------
__global__ __launch_bounds__(256, 5) void asi_k(
    const unsigned short* __restrict__ h_b, const unsigned short* __restrict__ x_b,
    const int* __restrict__ idx_s, const int* __restrict__ idx_t,
    const unsigned short* __restrict__ Wasi,
    const unsigned short* __restrict__ Wm0, const unsigned short* __restrict__ Wm1,
    const unsigned short* __restrict__ Wm2, const unsigned short* __restrict__ Wm3,
    float* __restrict__ out_m)
{
    __shared__ char A[64 * 256];
    __shared__ char B[64 * 256];
    const int tid = threadIdx.x;
    const int l = tid & 63, wm = tid >> 6;
    const int fr = l & 15, fq = (l >> 4) << 2;
    const int row0 = blockIdx.x * 64;

    f32x4 acc[2][4];
    zacc(acc);

    for (int c = 0; c < 3; ++c) {
        s16x8 aw[2][4];
        load_w<2, 4>(Wasi + (size_t)(wm * 32) * 384 + c * 128, 384, l, aw);
        #pragma unroll
        for (int u = 0; u < 4; ++u) {
            const int flat = tid + u * 256;
            const int row = flat >> 4;
            const int k8 = (flat & 15) << 3;
            const int grow = row0 + row;
            s16x8 v = {0, 0, 0, 0, 0, 0, 0, 0};
            if (grow < EE) {
                const unsigned short* src =
                    (c == 0) ? h_b + (size_t)idx_s[grow] * 128
                  : (c == 1) ? h_b + (size_t)idx_t[grow] * 128
                             : x_b + (size_t)grow * 128;
                v = *(const s16x8*)&src[k8];
            }
            *(s16x8*)(A + row * 256 + ((k8 * 2) ^ ((row & 7) << 4))) = v;
        }
        __syncthreads();
        gemm_pre<2, 4, 4>(aw, A, 256, 0, l, acc);
        __syncthreads();
    }

    f32x4 x[2][4];
    #pragma unroll
    for (int mt = 0; mt < 2; ++mt)
        #pragma unroll
        for (int nf = 0; nf < 4; ++nf)
            #pragma unroll
            for (int q = 0; q < 4; ++q)
                x[mt][nf][q] = act_silu(acc[mt][nf][q]);
    #pragma unroll
    for (int mt = 0; mt < 2; ++mt)
        #pragma unroll
        for (int nf = 0; nf < 4; ++nf)
            packA(A, 256, nf * 16 + fr, wm * 32 + mt * 16 + fq, x[mt][nf]);
    __syncthreads();

    res_layer<false, 4>(A, B, Wm0, Wm1, wm, 0, l, x, nullptr);
    res_layer<false, 4>(A, B, Wm2, Wm3, wm, 0, l, x, nullptr);

    #pragma unroll
    for (int mt = 0; mt < 2; ++mt)
        #pragma unroll
        for (int nf = 0; nf < 4; ++nf) {
            const int row = nf * 16 + fr;
            const int grow = row0 + row;
            if (grow >= EE) continue;
            const int of0 = wm * 32 + mt * 16 + fq;
            s16x4 xv = *(const s16x4*)&x_b[(size_t)grow * 128 + of0];
            f32x4 o;
            #pragma unroll
            for (int q = 0; q < 4; ++q)
                o[q] = (x[mt][nf][q] + bf2f((unsigned short)xv[q])) * C_INV;
            *(f32x4*)&out_m[(size_t)grow * 128 + of0] = o;
        }
}

// ---------------------------------------------------------------------------
// rbf scale: scale = rbf3 @ W_t_rbf -> bf16
// ---------------------------------------------------------------------------
__global__ __launch_bounds__(256) void rbf_scale_k(
    const float* __restrict__ A, const float* __restrict__ W,
    unsigned short* __restrict__ out, int M)
{
    __shared__ float Ws[16][128];
    const int tid = threadIdx.x;
    #pragma unroll
    for (int t = tid; t < 512; t += 256) {
        int kk = t >> 5, c4 = (t & 31) << 2;
        *(float4*)&Ws[kk][c4] = *(const float4*)(W + kk * 128 + c4);
    }
    __syncthreads();
    const int tx = tid & 31, ty = tid >> 5;
    const int row0 = blockIdx.x * 128;
    #pragma unroll
    for (int i = 0; i < 16; ++i) {
        const int row = row0 + ty + i * 8;
        if (row >= M) continue;
        float av[16];
        #pragma unroll
        for (int j = 0; j < 4; ++j) {
            float4 a = *(const float4*)(A + (size_t)row * 16 + j * 4);
            av[j * 4] = a.x; av[j * 4 + 1] = a.y; av[j * 4 + 2] = a.z; av[j * 4 + 3] = a.w;
        }
        f32x4 s = {0.f, 0.f, 0.f, 0.f};
        #pragma unroll
        for (int k = 0; k < 16; ++k) {
            float4 wv = *(const float4*)&Ws[k][tx * 4];
            s[0] += av[k] * wv.x; s[1] += av[k] * wv.y;
            s[2] += av[k] * wv.z; s[3] += av[k] * wv.w;
        }
        store_bf4(&out[(size_t)row * 128 + tx * 4], s);
    }
}

// ---------------------------------------------------------------------------
// counting sort + segment-sum
// ---------------------------------------------------------------------------
__global__ void hist_k(const int* __restrict__ idxt, int* __restrict__ cnt)
{
    int i = blockIdx.x * 256 + threadIdx.x;
    if (i < EE) atomicAdd(&cnt[idxt[i]], 1);
}

__global__ __launch_bounds__(256) void scan_k(const int* __restrict__ cnt,
                                              int* __restrict__ start, int* __restrict__ wrk)
{
    __shared__ int ps[256];
    const int t = threadIdx.x;
    int s = 0;
    for (int j = 0; j < 40; ++j) {
        int idx = t * 40 + j;
        if (idx < NA) s += cnt[idx];
    }
    ps[t] = s;
    __syncthreads();
    for (int off = 1; off < 256; off <<= 1) {
        int v = (t >= off) ? ps[t - off] : 0;
        __syncthreads();
        ps[t] += v;
        __syncthreads();
    }
    int run = ps[t] - s;
    for (int j = 0; j < 40; ++j) {
        int idx = t * 40 + j;
        if (idx < NA) {
            start[idx] = run;
            wrk[idx] = run;
            run += cnt[idx];
        }
    }
    if (t == 255) start[NA] = ps[255];
}

__global__ void place_k(const int* __restrict__ idxt, int* __restrict__ wrk,
                        int* __restrict__ order)
{
    int i = blockIdx.x * 256 + threadIdx.x;
    if (i < EE) {
        int pos = atomicAdd(&wrk[idxt[i]], 1);
        order[pos] = i;
    }
}

__global__ __launch_bounds__(256) void segsum_k(
    const unsigned short* __restrict__ x_b, const float* __restrict__ rbf_h,
    const float* __restrict__ Wae, const int* __restrict__ start,
    const int* __restrict__ order, float* __restrict__ h2)
{
    const int tid = threadIdx.x;
    const int l = tid & 63, w = tid >> 6;
    const int a = blockIdx.x * 4 + w;
    if (a >= NA) return;

    float wc[32];
    #pragma unroll
    for (int j = 0; j < 16; ++j) {
        f32x2 v = *(const f32x2*)(Wae + j * 128 + 2 * l);
        wc[2 * j] = v[0]; wc[2 * j + 1] = v[1];
    }

    const int s = start[a], e_end = start[a + 1];
    float acc0 = 0.f, acc1 = 0.f;
    for (int i = s; i < e_end; ++i) {
        const int e = __builtin_amdgcn_readfirstlane(order[i]);
        const unsigned int xv = *(const unsigned int*)(x_b + (size_t)e * 128 + 2 * l);
        const float* rp = rbf_h + (size_t)e * 16;
        float c0 = 0.f, c1 = 0.f;
        #pragma unroll
        for (int j = 0; j < 16; ++j) {
            float r = rp[j];
            c0 += r * wc[2 * j];
            c1 += r * wc[2 * j + 1];
        }
        acc0 += bf2f((unsigned short)(xv & 0xffff)) * c0;
        acc1 += bf2f((unsigned short)(xv >> 16)) * c1;
    }
    f32x2 o; o[0] = acc0; o[1] = acc1;
    *(f32x2*)&h2[(size_t)a * 128 + 2 * l] = o;
}

// ---------------------------------------------------------------------------
// weight conversions
// ---------------------------------------------------------------------------
__global__ void wconv_k(const float* __restrict__ Wbil, unsigned short* __restrict__ WT)
{
    int t = blockIdx.x * 256 + threadIdx.x;
    int u = t >> 10, k = t & 1023, j = k >> 6, c = k & 63;
    WT[t] = f2bf(Wbil[(size_t)(c * 16 + j) * 64 + u]);
}

struct WDesc { const float* src; int K; int N; int off; };
struct WTab  { WDesc d[21]; };

__global__ void wconvall_k(WTab tab, unsigned short* __restrict__ dst)
{
    WDesc d = tab.d[blockIdx.x];
    const int tot = d.K * d.N;
    for (int i = threadIdx.x; i < tot; i += 256) {
        int n = i / d.K, k = i - n * d.K;
        dst[d.off + i] = f2bf(d.src[(size_t)k * d.N + n]);
    }
}

// ---------------------------------------------------------------------------
// bilinear v8 (unchanged from r12): C[j][k] precompute + phase D + fused st3/ts3
// ---------------------------------------------------------------------------
__global__ __launch_bounds__(512) void bilinear8_k(
    const unsigned short* __restrict__ mkt,
    const float* __restrict__ rbfW1,
    const float* __restrict__ sph,
    const int*   __restrict__ id3kt,
    const unsigned short* __restrict__ WT,
    const unsigned short* __restrict__ Wst3,
    const unsigned short* __restrict__ Wts3,
    unsigned short* __restrict__ yst,
    unsigned short* __restrict__ yts)
{
    __shared__ unsigned short aS[32 * 1024];   // 64 KB (a-tile / partials / xb)
    __shared__ float Cs[32 * 128];             // 16 KB (per-edge C[16][8] f32)
    float* pS = (float*)aS;
    float* sphS = (float*)(aS + 16384);        // upper 32 KB of aS: coef staging
    float* rbS  = sphS + 32 * 56;

    const int tid = threadIdx.x;
    const int l   = tid & 63;
    const int w   = tid >> 6;
    const int e0  = blockIdx.x * 32;
    const int fr  = l & 15;
    const int fq  = (l >> 4) << 2;

    // ---- stage coefficients (coalesced block copies into upper aS) ----
    {
        const f32x4* sg = (const f32x4*)(sph + (size_t)e0 * 56);
        for (int u = tid; u < 448; u += 512) ((f32x4*)sphS)[u] = sg[u];
        const f32x4* rg = (const f32x4*)(rbfW1 + (size_t)e0 * 112);
        for (int u = tid; u < 896; u += 512) ((f32x4*)rbS)[u] = rg[u];
    }

    // ---- issue id loads + gathers for all 4 rounds (hide under C compute) ----
    int ids[4][8];
    #pragma unroll
    for (int r = 0; r < 4; ++r) {
        const int eG = e0 + r * 8 + w;
        #pragma unroll
        for (int k = 0; k < 8; ++k) ids[r][k] = id3kt[eG * 8 + k];
    }
    unsigned int m0[8], m1[8], m2v[8], m3[8];
    #pragma unroll
    for (int k = 0; k < 8; ++k) m0[k] = mkt[(size_t)ids[0][k] * 64 + l];
    #pragma unroll
    for (int k = 0; k < 8; ++k) m1[k] = mkt[(size_t)ids[1][k] * 64 + l];
    #pragma unroll
    for (int k = 0; k < 8; ++k) m2v[k] = mkt[(size_t)ids[2][k] * 64 + l];
    #pragma unroll
    for (int k = 0; k < 8; ++k) m3[k] = mkt[(size_t)ids[3][k] * 64 + l];

    __syncthreads();   // coef staged

    // ---- C compute: thread (e = tid>>4, j = tid&15) -> C[e][j][0..7] ----
    {
        const int e = tid >> 4;
        const int j = tid & 15;
        float rb[7];
        #pragma unroll
        for (int s = 0; s < 7; ++s) rb[s] = rbS[e * 112 + j * 7 + s];
        float cr[8];
        #pragma unroll
        for (int k = 0; k < 8; ++k) {
            float a = 0.f;
            #pragma unroll
            for (int s = 0; s < 7; ++s)
                a += rb[s] * sphS[e * 56 + k * 7 + s];
            cr[k] = a;
        }
        f32x4 lo = {cr[0], cr[1], cr[2], cr[3]};
        f32x4 hi = {cr[4], cr[5], cr[6], cr[7]};
        *(f32x4*)&Cs[e * 128 + j * 8]     = lo;
        *(f32x4*)&Cs[e * 128 + j * 8 + 4] = hi;
    }
    __syncthreads();   // C ready; coef staging dead -> aS fully writable

    // ---- A-C rounds: av[j] = sum_k C[j][k] * m2[k]  (per-lane c) ----
    #pragma unroll
    for (int r = 0; r < 4; ++r) {
        const int eL = r * 8 + w;
        const float* Ce = &Cs[eL * 128];
        const unsigned int* mm = (r == 0) ? m0 : (r == 1) ? m1 : (r == 2) ? m2v : m3;
        float mv[8];
        #pragma unroll
        for (int k = 0; k < 8; ++k) mv[k] = __uint_as_float(mm[k] << 16);
        unsigned short* arow = aS + eL * 1024;
        const int lsw = l ^ ((eL & 7) << 3);
        #pragma unroll
        for (int j = 0; j < 16; ++j) {
            f32x4 c0 = *(const f32x4*)&Ce[j * 8];
            f32x4 c1 = *(const f32x4*)&Ce[j * 8 + 4];
            float av = c0[0] * mv[0] + c0[1] * mv[1] + c0[2] * mv[2] + c0[3] * mv[3]
                     + c1[0] * mv[4] + c1[1] * mv[5] + c1[2] * mv[6] + c1[3] * mv[7];
            arow[j * 64 + lsw] = f2bf(av);
        }
    }

    // ---- load B-fragments for phase D (after peak VGPR region) ----
    s16x8 bfrag[4][4];
    {
        const int u  = l & 15;
        const int kh = w * 128 + ((l >> 4) << 3);
        #pragma unroll
        for (int nt = 0; nt < 4; ++nt)
            #pragma unroll
            for (int kq = 0; kq < 4; ++kq)
                bfrag[nt][kq] = *(const s16x8*)&WT[(size_t)(nt * 16 + u) * 1024 + kh + kq * 32];
    }
    __syncthreads();

    // ---- phase D: wave w owns K-slice [w*128, w*128+128) ----
    f32x4 acc[2][4];
    #pragma unroll
    for (int mt = 0; mt < 2; ++mt)
        #pragma unroll
        for (int nt = 0; nt < 4; ++nt)
            acc[mt][nt] = (f32x4){0.f, 0.f, 0.f, 0.f};

    const int kbase = w * 128 + ((l >> 4) << 3);
    #pragma unroll
    for (int kq = 0; kq < 4; ++kq) {
        s16x8 afr[2];
        #pragma unroll
        for (int mt = 0; mt < 2; ++mt) {
            const int row = mt * 16 + (l & 15);
            const int kk  = (kbase + kq * 32) ^ ((row & 7) << 3);
            afr[mt] = *(const s16x8*)&aS[row * 1024 + kk];
        }
        #pragma unroll
        for (int mt = 0; mt < 2; ++mt)
            #pragma unroll
            for (int nt = 0; nt < 4; ++nt)
                acc[mt][nt] = __builtin_amdgcn_mfma_f32_16x16x32_bf16(
                    afr[mt], bfrag[nt][kq], acc[mt][nt], 0, 0, 0);
    }
    __syncthreads();   // aS reads done before pS overwrite

    #pragma unroll
    for (int mt = 0; mt < 2; ++mt)
        #pragma unroll
        for (int nt = 0; nt < 4; ++nt)
            #pragma unroll
            for (int q = 0; q < 4; ++q) {
                const int e = mt * 16 + ((l >> 4) << 2) + q;
                const int u = nt * 16 + (l & 15);
                pS[(w * 32 + e) * 64 + u] = acc[mt][nt][q];
            }
    __syncthreads();

    // ---- reduce 8 K-slices into regs ----
    f32x4 s;
    {
        const int e  = tid >> 4;
        const int u0 = (tid & 15) << 2;
        s = (f32x4){0.f, 0.f, 0.f, 0.f};
        #pragma unroll
        for (int ww = 0; ww < 8; ++ww)
            s += *(const f32x4*)&pS[(ww * 32 + e) * 64 + u0];
    }
    __syncthreads();   // all pS reads done

    // ---- xb -> bf16 swizzled LDS tile [32 rows][64 k] (RS=128B), aliases aS
    unsigned short* xbS = aS;
    {
        const int e  = tid >> 4;
        const int u0 = (tid & 15) << 2;
        uint2 p;
        p.x = cvtpk(s[0], s[1]);
        p.y = cvtpk(s[2], s[3]);
        *(uint2*)((char*)xbS + e * 128 + ((u0 * 2) ^ ((e & 7) << 4))) = p;
    }
    __syncthreads();

    // ---- fused st3 / ts3: waves 0-3 -> y_st quarters, waves 4-7 -> y_ts ----
    const unsigned short* Wsel = (w < 4) ? Wst3 : Wts3;
    unsigned short*       ysel = (w < 4) ? yst : yts;
    const int wmF = w & 3;

    s16x8 awF[2][2];
    load_w<2, 2>(Wsel + (size_t)(wmF * 32) * 64, 64, l, awF);
    f32x4 accF[2][2];
    zacc(accF);
    gemm_pre<2, 2, 2>(awF, (const char*)xbS, 128, 0, l, accF);

    #pragma unroll
    for (int mt = 0; mt < 2; ++mt)
        #pragma unroll
        for (int nf = 0; nf < 2; ++nf) {
            const int row = nf * 16 + fr;
            const int of0 = wmF * 32 + mt * 16 + fq;
            f32x4 v;
            #pragma unroll
            for (int q = 0; q < 4; ++q) v[q] = act_silu(accF[mt][nf][q]);
            store_bf4(&ysel[(size_t)(e0 + row) * 128 + of0], v);
        }
}

// ---------------------------------------------------------------------------
// launch
// ---------------------------------------------------------------------------
extern "C" void kernel_launch(void* const* d_in, const int* in_sizes, int n_in,
                              void* d_out, int out_size, void* d_ws, size_t ws_size,
                              hipStream_t stream)
{
    const float* m_st      = (const float*)d_in[1];
    const float* rbf_h     = (const float*)d_in[2];
    const float* rbf3      = (const float*)d_in[3];
    const float* cbf_rbfW1 = (const float*)d_in[4];
    const float* cbf_sph   = (const float*)d_in[5];
    const float* W_mlp_st  = (const float*)d_in[6];
    const float* W_m_kt    = (const float*)d_in[7];
    const float* W_t_rbf   = (const float*)d_in[8];
    const float* W_down    = (const float*)d_in[9];
    const float* W_bil     = (const float*)d_in[10];
    const float* W_st3     = (const float*)d_in[11];
    const float* W_ts3     = (const float*)d_in[12];
    const float* resb      = (const float*)d_in[13];
    const float* resa      = (const float*)d_in[14];
    const float* W_ae_rbf  = (const float*)d_in[15];
    const float* W_ae_in   = (const float*)d_in[16];
    const float* resat     = (const float*)d_in[17];
    const float* W_asi     = (const float*)d_in[18];
    const float* resm      = (const float*)d_in[19];
    const int*   idx_s     = (const int*)d_in[20];
    const int*   idx_t     = (const int*)d_in[21];
    const int*   idx_swap  = (const int*)d_in[22];
    const int*   id3_kt    = (const int*)d_in[23];

    float* h2 = (float*)d_ws;                               // NA x 128 f32
    unsigned short* scale_b = (unsigned short*)(h2 + (size_t)NA * 128);
    unsigned short* yst_b   = scale_b;                      // alias (scale dead first)
    unsigned short* yts_b   = scale_b + (size_t)EE * 128;
    unsigned short* x_b     = yts_b + (size_t)EE * 128;
    unsigned short* mkt_b   = x_b + (size_t)EE * 128;
    unsigned short* xb_b    = mkt_b + (size_t)EE * 64;      // (unused)
    unsigned short* h_b     = xb_b + (size_t)EE * 64;
    unsigned short* WTbil   = h_b + (size_t)NA * 128;
    unsigned short* WTall   = WTbil + 65536;
    int* cnt   = (int*)(WTall + 352256);
    int* start = cnt + NA;
    int* wrk   = start + NA + 1;
    int* order = wrk + NA;

    float* out_h = (float*)d_out;
    float* out_m = out_h + (size_t)NA * 128;

    const dim3 blk(256);
    const dim3 blk5(512);
    const int gE128 = (EE + 127) / 128;   // 938  (rbf_scale)
    const int gE64  = (EE + 63) / 64;     // 1875 (front/chain/asi)
    const int gN64  = (NA + 63) / 64;     // 157
    constexpr size_t SQ = 128 * 128;

    WTab tab; int off = 0; int oi = 0;
    auto put = [&](const float* s, int K, int N) {
        int o = off; tab.d[oi].src = s; tab.d[oi].K = K; tab.d[oi].N = N;
        tab.d[oi].off = o; ++oi; off += K * N; return o;
    };
    const int o_mlp  = put(W_mlp_st, 128, 128);
    const int o_mktw = put(W_m_kt, 128, 128);
    const int o_down = put(W_down, 128, 64);
    const int o_st3  = put(W_st3, 64, 128);
    const int o_ts3  = put(W_ts3, 64, 128);
    const int o_rb0  = put(resb, 128, 128);
    const int o_rb1  = put(resb + SQ, 128, 128);
    const int o_ra0  = put(resa, 128, 128);
    const int o_ra1  = put(resa + SQ, 128, 128);
    const int o_ra2  = put(resa + 2 * SQ, 128, 128);
    const int o_ra3  = put(resa + 3 * SQ, 128, 128);
    const int o_aein = put(W_ae_in, 128, 128);
    const int o_rat0 = put(resat, 128, 128);
    const int o_rat1 = put(resat + SQ, 128, 128);
    const int o_rat2 = put(resat + 2 * SQ, 128, 128);
    const int o_rat3 = put(resat + 3 * SQ, 128, 128);
    const int o_asi  = put(W_asi, 384, 128);
    const int o_rm0  = put(resm, 128, 128);
    const int o_rm1  = put(resm + SQ, 128, 128);
    const int o_rm2  = put(resm + 2 * SQ, 128, 128);
    const int o_rm3  = put(resm + 3 * SQ, 128, 128);

    hipMemsetAsync(cnt, 0, NA * sizeof(int), stream);
    wconv_k<<<65536 / 256, blk, 0, stream>>>(W_bil, WTbil);
    wconvall_k<<<21, blk, 0, stream>>>(tab, WTall);
    hist_k<<<(EE + 255) / 256, blk, 0, stream>>>(idx_t, cnt);
    scan_k<<<1, blk, 0, stream>>>(cnt, start, wrk);
    place_k<<<(EE + 255) / 256, blk, 0, stream>>>(idx_t, wrk, order);

    rbf_scale_k<<<gE128, blk, 0, stream>>>(rbf3, W_t_rbf, scale_b, EE);
    front_k<<<gE64, blk, 0, stream>>>(m_st, scale_b, WTall + o_mktw, WTall + o_down, mkt_b);
    bilinear8_k<<<EE / 32, blk5, 0, stream>>>(
        mkt_b, cbf_rbfW1, cbf_sph, id3_kt, WTbil,
        WTall + o_st3, WTall + o_ts3, yst_b, yts_b);
    chain_k<<<gE64, blk, 0, stream>>>(
        m_st, yst_b, yts_b, idx_swap,
        WTall + o_mlp, WTall + o_rb0, WTall + o_rb1,
        WTall + o_ra0, WTall + o_ra1, WTall + o_ra2, WTall + o_ra3,
        x_b);
    segsum_k<<<(NA + 3) / 4, blk, 0, stream>>>(x_b, rbf_h, W_ae_rbf, start, order, h2);
    atom_k<<<gN64, blk5, 0, stream>>>(
        h2, WTall + o_aein,
        WTall + o_rat0, WTall + o_rat1, WTall + o_rat2, WTall + o_rat3,
        out_h, h_b);
    asi_k<<<gE64, blk, 0, stream>>>(
        h_b, x_b, idx_s, idx_t,
        WTall + o_asi,
        WTall + o_rm0, WTall + o_rm1, WTall + o_rm2, WTall + o_rm3,
        out_m);
}

// Round 14
// 594.262 us; speedup vs baseline: 1.1889x; 1.1889x over previous
//
#include <hip/hip_runtime.h>

// ---------------------------------------------------------------------------
// GemNet InteractionBlock forward, MI355X (gfx950).
// Round 14: r12 structure restored (best: 629us); rbf_scale fused into
// front_k (scale computed in-kernel from rbf3/W_t_rbf, f32, LDS-staged).
// ---------------------------------------------------------------------------

#define EE 120000
#define NA 10000

constexpr float C_INV = 0.70710678118654752440f;

using f32x4 = __attribute__((ext_vector_type(4))) float;
using f32x2 = __attribute__((ext_vector_type(2))) float;
using s16x8 = __attribute__((ext_vector_type(8))) short;
using s16x4 = __attribute__((ext_vector_type(4))) short;

__device__ __forceinline__ float act_silu(float x) { return x / (1.0f + __expf(-x)); }

__device__ __forceinline__ unsigned short f2bf(float f) {
    unsigned int u = __float_as_uint(f);
    u += 0x7fffu + ((u >> 16) & 1u);
    return (unsigned short)(u >> 16);
}
__device__ __forceinline__ float bf2f(unsigned short h) {
    return __uint_as_float(((unsigned int)h) << 16);
}
__device__ __forceinline__ unsigned int cvtpk(float a, float b) {
    unsigned int r;
    asm("v_cvt_pk_bf16_f32 %0, %1, %2" : "=v"(r) : "v"(a), "v"(b));
    return r;
}

// ---------------------------------------------------------------------------
// weight fragment preload + MFMA with preloaded weights (b from swizzled LDS)
// ---------------------------------------------------------------------------
template<int MT, int KQ>
__device__ __forceinline__ void load_w(const unsigned short* __restrict__ W, int KW,
                                       int l, s16x8 (&a)[MT][KQ])
{
    const int fr = l & 15;
    const int k8 = (l >> 4) << 3;
    #pragma unroll
    for (int mt = 0; mt < MT; ++mt)
        #pragma unroll
        for (int kq = 0; kq < KQ; ++kq)
            a[mt][kq] = *(const s16x8*)&W[(size_t)(mt * 16 + fr) * KW + kq * 32 + k8];
}

template<int MT, int NF, int KQ>
__device__ __forceinline__ void gemm_pre(
    const s16x8 (&a)[MT][KQ], const char* ldsB, int RS,
    int rowBase, int l, f32x4 (&acc)[MT][NF])
{
    const int fr = l & 15;
    const int k8 = (l >> 4) << 3;
    #pragma unroll
    for (int kq = 0; kq < KQ; ++kq) {
        s16x8 b[NF];
        #pragma unroll
        for (int nf = 0; nf < NF; ++nf) {
            const int row = rowBase + nf * 16 + fr;
            const int kb  = ((kq * 32 + k8) * 2) ^ ((row & 7) << 4);
            b[nf] = *(const s16x8*)(ldsB + row * RS + kb);
        }
        #pragma unroll
        for (int mt = 0; mt < MT; ++mt)
            #pragma unroll
            for (int nf = 0; nf < NF; ++nf)
                acc[mt][nf] = __builtin_amdgcn_mfma_f32_16x16x32_bf16(
                    a[mt][kq], b[nf], acc[mt][nf], 0, 0, 0);
    }
}

template<int MT, int NF>
__device__ __forceinline__ void zacc(f32x4 (&acc)[MT][NF])
{
    #pragma unroll
    for (int mt = 0; mt < MT; ++mt)
        #pragma unroll
        for (int nf = 0; nf < NF; ++nf)
            acc[mt][nf] = (f32x4){0.f, 0.f, 0.f, 0.f};
}

__device__ __forceinline__ void packA(char* lds, int RS, int row, int outF0, f32x4 v)
{
    uint2 p;
    p.x = cvtpk(v[0], v[1]);
    p.y = cvtpk(v[2], v[3]);
    *(uint2*)(lds + row * RS + ((outF0 * 2) ^ ((row & 7) << 4))) = p;
}

__device__ __forceinline__ void store_bf4(unsigned short* dst, f32x4 v)
{
    uint2 p;
    p.x = cvtpk(v[0], v[1]);
    p.y = cvtpk(v[2], v[3]);
    *(uint2*)dst = p;
}

// stage ROWS x 128 f32 -> swizzled bf16 LDS (RS=256), 512 threads
template<int ROWS>
__device__ __forceinline__ void stage_f32(char* lds, const float* __restrict__ src,
                                          int row0, int M, int tid)
{
    #pragma unroll
    for (int u = 0; u < ROWS * 16 / 512; ++u) {
        const int flat = tid + u * 512;
        const int row  = flat >> 4;
        const int k8   = (flat & 15) << 3;
        const int grow = row0 + row;
        uint4 val = {0u, 0u, 0u, 0u};
        if (grow < M) {
            const float* p = src + (size_t)grow * 128 + k8;
            f32x4 lo = *(const f32x4*)p;
            f32x4 hi = *(const f32x4*)(p + 4);
            val.x = cvtpk(lo[0], lo[1]);
            val.y = cvtpk(lo[2], lo[3]);
            val.z = cvtpk(hi[0], hi[1]);
            val.w = cvtpk(hi[2], hi[3]);
        }
        *(uint4*)(lds + row * 256 + ((k8 * 2) ^ ((row & 7) << 4))) = val;
    }
}

// ---------------------------------------------------------------------------
// one ResidualLayer (8 waves: wm 0..3 feat-quarters, wn 0..1 row-halves)
// ---------------------------------------------------------------------------
template<bool MSTM, int NF>
__device__ __forceinline__ void res_layer(
    char* A, char* B,
    const unsigned short* W0, const unsigned short* W1,
    int wm, int wn, int l, f32x4 (&x)[2][NF],
    const s16x4 (*ms)[NF])
{
    const int fr = l & 15;
    const int fq = (l >> 4) << 2;

    s16x8 aw[2][4];
    load_w<2, 4>(W0 + (size_t)(wm * 32) * 128, 128, l, aw);
    f32x4 acc[2][NF];
    zacc(acc);
    gemm_pre<2, NF, 4>(aw, A, 256, wn * NF * 16, l, acc);

    s16x8 aw1[2][4];
    load_w<2, 4>(W1 + (size_t)(wm * 32) * 128, 128, l, aw1);   // issue before barrier

    #pragma unroll
    for (int mt = 0; mt < 2; ++mt)
        #pragma unroll
        for (int nf = 0; nf < NF; ++nf) {
            const int row = wn * NF * 16 + nf * 16 + fr;
            const int of0 = wm * 32 + mt * 16 + fq;
            f32x4 v;
            #pragma unroll
            for (int q = 0; q < 4; ++q) v[q] = act_silu(acc[mt][nf][q]);
            packA(B, 256, row, of0, v);
        }
    __syncthreads();

    zacc(acc);
    gemm_pre<2, NF, 4>(aw1, B, 256, wn * NF * 16, l, acc);
    #pragma unroll
    for (int mt = 0; mt < 2; ++mt)
        #pragma unroll
        for (int nf = 0; nf < NF; ++nf) {
            const int row = wn * NF * 16 + nf * 16 + fr;
            const int of0 = wm * 32 + mt * 16 + fq;
            #pragma unroll
            for (int q = 0; q < 4; ++q)
                x[mt][nf][q] = (x[mt][nf][q] + act_silu(acc[mt][nf][q])) * C_INV;
            if (MSTM) {
                #pragma unroll
                for (int q = 0; q < 4; ++q)
                    x[mt][nf][q] = (x[mt][nf][q] +
                                    bf2f((unsigned short)ms[mt][nf][q])) * C_INV;
            }
            packA(A, 256, row, of0, x[mt][nf]);
        }
    __syncthreads();
}

__device__ __forceinline__ s16x4 read_frag(const char* lds, int row, int of0)
{
    return *(const s16x4*)(lds + row * 256 + ((of0 * 2) ^ ((row & 7) << 4)));
}

// ---------------------------------------------------------------------------
// front: scale = rbf3 @ W_t_rbf (in-kernel, f32);
//        tpre = act(m_st@W_m_kt)*scale ; mkt = act(tpre@W_down)
// ---------------------------------------------------------------------------
__global__ __launch_bounds__(512, 4) void front_k(
    const float* __restrict__ m_st, const float* __restrict__ rbf3,
    const float* __restrict__ Wtrbf,
    const unsigned short* __restrict__ Wmkt, const unsigned short* __restrict__ Wdown,
    unsigned short* __restrict__ mkt_b)
{
    __shared__ char A[128 * 256];      // 32 KB
    __shared__ float Wt[16 * 128];     // 8 KB   W_t_rbf f32
    __shared__ float R3[128 * 17];     // 8.5 KB rbf3 rows (pad 17: conflict-free)
    const int tid = threadIdx.x;
    const int l = tid & 63, w = tid >> 6, wm = w & 3, wn = w >> 2;
    const int fr = l & 15, fq = (l >> 4) << 2;
    const int row0 = blockIdx.x * 128;

    s16x8 aw[2][4];
    load_w<2, 4>(Wmkt + (size_t)(wm * 32) * 128, 128, l, aw);

    // stage Wt + rbf3 rows
    for (int u = tid; u < 2048; u += 512) Wt[u] = Wtrbf[u];
    for (int u = tid; u < 2048; u += 512) {
        const int row = u >> 4, k = u & 15;
        const int grow = row0 + row;
        R3[row * 17 + k] = (grow < EE) ? rbf3[(size_t)grow * 16 + k] : 0.f;
    }

    stage_f32<128>(A, m_st, row0, EE, tid);
    __syncthreads();

    f32x4 acc[2][4];
    zacc(acc);
    gemm_pre<2, 4, 4>(aw, A, 256, wn * 64, l, acc);

    s16x8 aw2[1][4];
    load_w<1, 4>(Wdown + (size_t)(wm * 16) * 128, 128, l, aw2);

    __syncthreads();
    #pragma unroll
    for (int mt = 0; mt < 2; ++mt)
        #pragma unroll
        for (int nf = 0; nf < 4; ++nf) {
            const int row = wn * 64 + nf * 16 + fr;
            const int grow = row0 + row;
            const int of0 = wm * 32 + mt * 16 + fq;
            f32x4 v = {0.f, 0.f, 0.f, 0.f};
            if (grow < EE) {
                f32x4 sc = {0.f, 0.f, 0.f, 0.f};
                #pragma unroll
                for (int k = 0; k < 16; ++k) {
                    const float r = R3[row * 17 + k];
                    f32x4 wv = *(const f32x4*)&Wt[k * 128 + of0];
                    sc += r * wv;
                }
                #pragma unroll
                for (int q = 0; q < 4; ++q)
                    v[q] = act_silu(acc[mt][nf][q]) * sc[q];
            }
            packA(A, 256, row, of0, v);
        }
    __syncthreads();

    f32x4 acc2[1][4];
    zacc(acc2);
    gemm_pre<1, 4, 4>(aw2, A, 256, wn * 64, l, acc2);
    #pragma unroll
    for (int nf = 0; nf < 4; ++nf) {
        const int row = wn * 64 + nf * 16 + fr;
        const int grow = row0 + row;
        if (grow >= EE) continue;
        const int of0 = wm * 16 + fq;
        f32x4 v;
        #pragma unroll
        for (int q = 0; q < 4; ++q) v[q] = act_silu(acc2[0][nf][q]);
        store_bf4(&mkt_b[(size_t)grow * 64 + of0], v);
    }
}

// ---------------------------------------------------------------------------
// chain: x_skip + (y_st + y_ts[swap]) merge + resb + m_st merge + resa x2
// ---------------------------------------------------------------------------
__global__ __launch_bounds__(512, 4) void chain_k(
    const float* __restrict__ m_st,
    const unsigned short* __restrict__ yst, const unsigned short* __restrict__ yts,
    const int* __restrict__ idx_swap,
    const unsigned short* __restrict__ Wmlp,
    const unsigned short* __restrict__ Wrb0, const unsigned short* __restrict__ Wrb1,
    const unsigned short* __restrict__ Wra0, const unsigned short* __restrict__ Wra1,
    const unsigned short* __restrict__ Wra2, const unsigned short* __restrict__ Wra3,
    unsigned short* __restrict__ xb_out)
{
    __shared__ char A[128 * 256];
    __shared__ char B[128 * 256];
    const int tid = threadIdx.x;
    const int l = tid & 63, w = tid >> 6, wm = w & 3, wn = w >> 2;
    const int fr = l & 15, fq = (l >> 4) << 2;
    const int row0 = blockIdx.x * 128;

    s16x8 aw[2][4];
    load_w<2, 4>(Wmlp + (size_t)(wm * 32) * 128, 128, l, aw);

    stage_f32<128>(A, m_st, row0, EE, tid);
    __syncthreads();

    f32x4 acc[2][4];
    zacc(acc);
    gemm_pre<2, 4, 4>(aw, A, 256, wn * 64, l, acc);

    s16x4 ms[2][4];
    #pragma unroll
    for (int mt = 0; mt < 2; ++mt)
        #pragma unroll
        for (int nf = 0; nf < 4; ++nf)
            ms[mt][nf] = read_frag(A, wn * 64 + nf * 16 + fr, wm * 32 + mt * 16 + fq);

    f32x4 x[2][4];
    #pragma unroll
    for (int mt = 0; mt < 2; ++mt)
        #pragma unroll
        for (int nf = 0; nf < 4; ++nf) {
            const int row = wn * 64 + nf * 16 + fr;
            const int grow = row0 + row;
            const int of0 = wm * 32 + mt * 16 + fq;
            if (grow < EE) {
                s16x4 a = *(const s16x4*)&yst[(size_t)grow * 128 + of0];
                const int sw = idx_swap[grow];
                s16x4 b = *(const s16x4*)&yts[(size_t)sw * 128 + of0];
                #pragma unroll
                for (int q = 0; q < 4; ++q)
                    x[mt][nf][q] = (acc[mt][nf][q] +
                        (bf2f((unsigned short)a[q]) + bf2f((unsigned short)b[q])) * C_INV) * C_INV;
            } else {
                x[mt][nf] = (f32x4){0.f, 0.f, 0.f, 0.f};
            }
        }
    __syncthreads();
    #pragma unroll
    for (int mt = 0; mt < 2; ++mt)
        #pragma unroll
        for (int nf = 0; nf < 4; ++nf)
            packA(A, 256, wn * 64 + nf * 16 + fr, wm * 32 + mt * 16 + fq, x[mt][nf]);
    __syncthreads();

    res_layer<true , 4>(A, B, Wrb0, Wrb1, wm, wn, l, x, ms);
    res_layer<false, 4>(A, B, Wra0, Wra1, wm, wn, l, x, nullptr);
    res_layer<false, 4>(A, B, Wra2, Wra3, wm, wn, l, x, nullptr);

    #pragma unroll
    for (int mt = 0; mt < 2; ++mt)
        #pragma unroll
        for (int nf = 0; nf < 4; ++nf) {
            const int row = wn * 64 + nf * 16 + fr;
            const int grow = row0 + row;
            if (grow >= EE) continue;
            const int of0 = wm * 32 + mt * 16 + fq;
            store_bf4(&xb_out[(size_t)grow * 128 + of0], x[mt][nf]);
        }
}

// ---------------------------------------------------------------------------
// atom chain (64-row tiles, NF=2)
// ---------------------------------------------------------------------------
__global__ __launch_bounds__(512, 4) void atom_k(
    const float* __restrict__ h2,
    const unsigned short* __restrict__ Wae,
    const unsigned short* __restrict__ Wr0, const unsigned short* __restrict__ Wr1,
    const unsigned short* __restrict__ Wr2, const unsigned short* __restrict__ Wr3,
    float* __restrict__ out_h, unsigned short* __restrict__ h_b)
{
    __shared__ char A[64 * 256];
    __shared__ char B[64 * 256];
    const int tid = threadIdx.x;
    const int l = tid & 63, w = tid >> 6, wm = w & 3, wn = w >> 2;
    const int fr = l & 15, fq = (l >> 4) << 2;
    const int row0 = blockIdx.x * 64;

    s16x8 aw[2][4];
    load_w<2, 4>(Wae + (size_t)(wm * 32) * 128, 128, l, aw);

    #pragma unroll
    for (int u = 0; u < 2; ++u) {
        const int flat = tid + u * 512;
        const int row  = flat >> 4;
        const int k8   = (flat & 15) << 3;
        const int grow = row0 + row;
        uint4 val = {0u, 0u, 0u, 0u};
        if (grow < NA) {
            const float* p = h2 + (size_t)grow * 128 + k8;
            f32x4 lo = *(const f32x4*)p;
            f32x4 hi = *(const f32x4*)(p + 4);
            val.x = cvtpk(lo[0], lo[1]);
            val.y = cvtpk(lo[2], lo[3]);
            val.z = cvtpk(hi[0], hi[1]);
            val.w = cvtpk(hi[2], hi[3]);
        }
        *(uint4*)(A + row * 256 + ((k8 * 2) ^ ((row & 7) << 4))) = val;
    }
    __syncthreads();

    f32x4 acc[2][2];
    zacc(acc);
    gemm_pre<2, 2, 4>(aw, A, 256, wn * 32, l, acc);
    f32x4 x[2][2];
    #pragma unroll
    for (int mt = 0; mt < 2; ++mt)
        #pragma unroll
        for (int nf = 0; nf < 2; ++nf)
            #pragma unroll
            for (int q = 0; q < 4; ++q)
                x[mt][nf][q] = act_silu(acc[mt][nf][q]);
    __syncthreads();
    #pragma unroll
    for (int mt = 0; mt < 2; ++mt)
        #pragma unroll
        for (int nf = 0; nf < 2; ++nf)
            packA(A, 256, wn * 32 + nf * 16 + fr, wm * 32 + mt * 16 + fq, x[mt][nf]);
    __syncthreads();

    res_layer<false, 2>(A, B, Wr0, Wr1, wm, wn, l, x, nullptr);
    res_layer<false, 2>(A, B, Wr2, Wr3, wm, wn, l, x, nullptr);

    #pragma unroll
    for (int mt = 0; mt < 2; ++mt)
        #pragma unroll
        for (int nf = 0; nf < 2; ++nf) {
            const int row = wn * 32 + nf * 16 + fr;
            const int grow = row0 + row;
            if (grow >= NA) continue;
            const int of0 = wm * 32 + mt * 16 + fq;
            *(f32x4*)&out_h[(size_t)grow * 128 + of0] = x[mt][nf];
            store_bf4(&h_b[(size_t)grow * 128 + of0], x[mt][nf]);
        }
}

// ---------------------------------------------------------------------------
// ASI + res_m: m = act([h[s]|h[t]|x]@W_asi); res_m x2; out_m = (m + x)*C
// ---------------------------------------------------------------------------
__global__ __launch_bounds__(512, 4) void asi_k(
    const unsigned short* __restrict__ h_b, const unsigned short* __restrict__ x_b,
    const int* __restrict__ idx_s, const int* __restrict__ idx_t,
    const unsigned short* __restrict__ Wasi,
    const unsigned short* __restrict__ Wm0, const unsigned short* __restrict__ Wm1,
    const unsigned short* __restrict__ Wm2, const unsigned short* __restrict__ Wm3,
    float* __restrict__ out_m)
{
    __shared__ char A[128 * 256];
    __shared__ char B[128 * 256];
    const int tid = threadIdx.x;
    const int l = tid & 63, w = tid >> 6, wm = w & 3, wn = w >> 2;
    const int fr = l & 15, fq = (l >> 4) << 2;
    const int row0 = blockIdx.x * 128;

    f32x4 acc[2][4];
    zacc(acc);

    for (int c = 0; c < 3; ++c) {
        s16x8 aw[2][4];
        load_w<2, 4>(Wasi + (size_t)(wm * 32) * 384 + c * 128, 384, l, aw);
        #pragma unroll
        for (int u = 0; u < 4; ++u) {
            const int flat = tid + u * 512;
            const int row = flat >> 4;
            const int k8 = (flat & 15) << 3;
            const int grow = row0 + row;
            s16x8 v = {0, 0, 0, 0, 0, 0, 0, 0};
            if (grow < EE) {
                const unsigned short* src =
                    (c == 0) ? h_b + (size_t)idx_s[grow] * 128
                  : (c == 1) ? h_b + (size_t)idx_t[grow] * 128
                             : x_b + (size_t)grow * 128;
                v = *(const s16x8*)&src[k8];
            }
            *(s16x8*)(A + row * 256 + ((k8 * 2) ^ ((row & 7) << 4))) = v;
        }
        __syncthreads();
        gemm_pre<2, 4, 4>(aw, A, 256, wn * 64, l, acc);
        __syncthreads();
    }

    f32x4 x[2][4];
    #pragma unroll
    for (int mt = 0; mt < 2; ++mt)
        #pragma unroll
        for (int nf = 0; nf < 4; ++nf)
            #pragma unroll
            for (int q = 0; q < 4; ++q)
                x[mt][nf][q] = act_silu(acc[mt][nf][q]);
    #pragma unroll
    for (int mt = 0; mt < 2; ++mt)
        #pragma unroll
        for (int nf = 0; nf < 4; ++nf)
            packA(A, 256, wn * 64 + nf * 16 + fr, wm * 32 + mt * 16 + fq, x[mt][nf]);
    __syncthreads();

    res_layer<false, 4>(A, B, Wm0, Wm1, wm, wn, l, x, nullptr);
    res_layer<false, 4>(A, B, Wm2, Wm3, wm, wn, l, x, nullptr);

    #pragma unroll
    for (int mt = 0; mt < 2; ++mt)
        #pragma unroll
        for (int nf = 0; nf < 4; ++nf) {
            const int row = wn * 64 + nf * 16 + fr;
            const int grow = row0 + row;
            if (grow >= EE) continue;
            const int of0 = wm * 32 + mt * 16 + fq;
            s16x4 xv = *(const s16x4*)&x_b[(size_t)grow * 128 + of0];
            f32x4 o;
            #pragma unroll
            for (int q = 0; q < 4; ++q)
                o[q] = (x[mt][nf][q] + bf2f((unsigned short)xv[q])) * C_INV;
            *(f32x4*)&out_m[(size_t)grow * 128 + of0] = o;
        }
}

// ---------------------------------------------------------------------------
// counting sort + segment-sum
// ---------------------------------------------------------------------------
__global__ void hist_k(const int* __restrict__ idxt, int* __restrict__ cnt)
{
    int i = blockIdx.x * 256 + threadIdx.x;
    if (i < EE) atomicAdd(&cnt[idxt[i]], 1);
}

__global__ __launch_bounds__(256) void scan_k(const int* __restrict__ cnt,
                                              int* __restrict__ start, int* __restrict__ wrk)
{
    __shared__ int ps[256];
    const int t = threadIdx.x;
    int s = 0;
    for (int j = 0; j < 40; ++j) {
        int idx = t * 40 + j;
        if (idx < NA) s += cnt[idx];
    }
    ps[t] = s;
    __syncthreads();
    for (int off = 1; off < 256; off <<= 1) {
        int v = (t >= off) ? ps[t - off] : 0;
        __syncthreads();
        ps[t] += v;
        __syncthreads();
    }
    int run = ps[t] - s;
    for (int j = 0; j < 40; ++j) {
        int idx = t * 40 + j;
        if (idx < NA) {
            start[idx] = run;
            wrk[idx] = run;
            run += cnt[idx];
        }
    }
    if (t == 255) start[NA] = ps[255];
}

__global__ void place_k(const int* __restrict__ idxt, int* __restrict__ wrk,
                        int* __restrict__ order)
{
    int i = blockIdx.x * 256 + threadIdx.x;
    if (i < EE) {
        int pos = atomicAdd(&wrk[idxt[i]], 1);
        order[pos] = i;
    }
}

__global__ __launch_bounds__(256) void segsum_k(
    const unsigned short* __restrict__ x_b, const float* __restrict__ rbf_h,
    const float* __restrict__ Wae, const int* __restrict__ start,
    const int* __restrict__ order, float* __restrict__ h2)
{
    const int tid = threadIdx.x;
    const int l = tid & 63, w = tid >> 6;
    const int a = blockIdx.x * 4 + w;
    if (a >= NA) return;

    float wc[32];
    #pragma unroll
    for (int j = 0; j < 16; ++j) {
        f32x2 v = *(const f32x2*)(Wae + j * 128 + 2 * l);
        wc[2 * j] = v[0]; wc[2 * j + 1] = v[1];
    }

    const int s = start[a], e_end = start[a + 1];
    float acc0 = 0.f, acc1 = 0.f;
    for (int i = s; i < e_end; ++i) {
        const int e = __builtin_amdgcn_readfirstlane(order[i]);
        const unsigned int xv = *(const unsigned int*)(x_b + (size_t)e * 128 + 2 * l);
        const float* rp = rbf_h + (size_t)e * 16;
        float c0 = 0.f, c1 = 0.f;
        #pragma unroll
        for (int j = 0; j < 16; ++j) {
            float r = rp[j];
            c0 += r * wc[2 * j];
            c1 += r * wc[2 * j + 1];
        }
        acc0 += bf2f((unsigned short)(xv & 0xffff)) * c0;
        acc1 += bf2f((unsigned short)(xv >> 16)) * c1;
    }
    f32x2 o; o[0] = acc0; o[1] = acc1;
    *(f32x2*)&h2[(size_t)a * 128 + 2 * l] = o;
}

// ---------------------------------------------------------------------------
// weight conversions
// ---------------------------------------------------------------------------
__global__ void wconv_k(const float* __restrict__ Wbil, unsigned short* __restrict__ WT)
{
    int t = blockIdx.x * 256 + threadIdx.x;
    int u = t >> 10, k = t & 1023, j = k >> 6, c = k & 63;
    WT[t] = f2bf(Wbil[(size_t)(c * 16 + j) * 64 + u]);
}

struct WDesc { const float* src; int K; int N; int off; };
struct WTab  { WDesc d[21]; };

__global__ void wconvall_k(WTab tab, unsigned short* __restrict__ dst)
{
    WDesc d = tab.d[blockIdx.x];
    const int tot = d.K * d.N;
    for (int i = threadIdx.x; i < tot; i += 256) {
        int n = i / d.K, k = i - n * d.K;
        dst[d.off + i] = f2bf(d.src[(size_t)k * d.N + n]);
    }
}

// ---------------------------------------------------------------------------
// bilinear v8 (r12): C[j][k] precompute + phase D + fused st3/ts3
// ---------------------------------------------------------------------------
__global__ __launch_bounds__(512) void bilinear8_k(
    const unsigned short* __restrict__ mkt,
    const float* __restrict__ rbfW1,
    const float* __restrict__ sph,
    const int*   __restrict__ id3kt,
    const unsigned short* __restrict__ WT,
    const unsigned short* __restrict__ Wst3,
    const unsigned short* __restrict__ Wts3,
    unsigned short* __restrict__ yst,
    unsigned short* __restrict__ yts)
{
    __shared__ unsigned short aS[32 * 1024];   // 64 KB (a-tile / partials / xb)
    __shared__ float Cs[32 * 128];             // 16 KB (per-edge C[16][8] f32)
    float* pS = (float*)aS;
    float* sphS = (float*)(aS + 16384);        // upper 32 KB of aS: coef staging
    float* rbS  = sphS + 32 * 56;

    const int tid = threadIdx.x;
    const int l   = tid & 63;
    const int w   = tid >> 6;
    const int e0  = blockIdx.x * 32;
    const int fr  = l & 15;
    const int fq  = (l >> 4) << 2;

    // ---- stage coefficients (coalesced block copies into upper aS) ----
    {
        const f32x4* sg = (const f32x4*)(sph + (size_t)e0 * 56);
        for (int u = tid; u < 448; u += 512) ((f32x4*)sphS)[u] = sg[u];
        const f32x4* rg = (const f32x4*)(rbfW1 + (size_t)e0 * 112);
        for (int u = tid; u < 896; u += 512) ((f32x4*)rbS)[u] = rg[u];
    }

    // ---- issue id loads + gathers for all 4 rounds (hide under C compute) ----
    int ids[4][8];
    #pragma unroll
    for (int r = 0; r < 4; ++r) {
        const int eG = e0 + r * 8 + w;
        #pragma unroll
        for (int k = 0; k < 8; ++k) ids[r][k] = id3kt[eG * 8 + k];
    }
    unsigned int m0[8], m1[8], m2v[8], m3[8];
    #pragma unroll
    for (int k = 0; k < 8; ++k) m0[k] = mkt[(size_t)ids[0][k] * 64 + l];
    #pragma unroll
    for (int k = 0; k < 8; ++k) m1[k] = mkt[(size_t)ids[1][k] * 64 + l];
    #pragma unroll
    for (int k = 0; k < 8; ++k) m2v[k] = mkt[(size_t)ids[2][k] * 64 + l];
    #pragma unroll
    for (int k = 0; k < 8; ++k) m3[k] = mkt[(size_t)ids[3][k] * 64 + l];

    __syncthreads();   // coef staged

    // ---- C compute: thread (e = tid>>4, j = tid&15) -> C[e][j][0..7] ----
    {
        const int e = tid >> 4;
        const int j = tid & 15;
        float rb[7];
        #pragma unroll
        for (int s = 0; s < 7; ++s) rb[s] = rbS[e * 112 + j * 7 + s];
        float cr[8];
        #pragma unroll
        for (int k = 0; k < 8; ++k) {
            float a = 0.f;
            #pragma unroll
            for (int s = 0; s < 7; ++s)
                a += rb[s] * sphS[e * 56 + k * 7 + s];
            cr[k] = a;
        }
        f32x4 lo = {cr[0], cr[1], cr[2], cr[3]};
        f32x4 hi = {cr[4], cr[5], cr[6], cr[7]};
        *(f32x4*)&Cs[e * 128 + j * 8]     = lo;
        *(f32x4*)&Cs[e * 128 + j * 8 + 4] = hi;
    }
    __syncthreads();   // C ready; coef staging dead -> aS fully writable

    // ---- A-C rounds: av[j] = sum_k C[j][k] * m2[k]  (per-lane c) ----
    #pragma unroll
    for (int r = 0; r < 4; ++r) {
        const int eL = r * 8 + w;
        const float* Ce = &Cs[eL * 128];
        const unsigned int* mm = (r == 0) ? m0 : (r == 1) ? m1 : (r == 2) ? m2v : m3;
        float mv[8];
        #pragma unroll
        for (int k = 0; k < 8; ++k) mv[k] = __uint_as_float(mm[k] << 16);
        unsigned short* arow = aS + eL * 1024;
        const int lsw = l ^ ((eL & 7) << 3);
        #pragma unroll
        for (int j = 0; j < 16; ++j) {
            f32x4 c0 = *(const f32x4*)&Ce[j * 8];
            f32x4 c1 = *(const f32x4*)&Ce[j * 8 + 4];
            float av = c0[0] * mv[0] + c0[1] * mv[1] + c0[2] * mv[2] + c0[3] * mv[3]
                     + c1[0] * mv[4] + c1[1] * mv[5] + c1[2] * mv[6] + c1[3] * mv[7];
            arow[j * 64 + lsw] = f2bf(av);
        }
    }

    // ---- load B-fragments for phase D (after peak VGPR region) ----
    s16x8 bfrag[4][4];
    {
        const int u  = l & 15;
        const int kh = w * 128 + ((l >> 4) << 3);
        #pragma unroll
        for (int nt = 0; nt < 4; ++nt)
            #pragma unroll
            for (int kq = 0; kq < 4; ++kq)
                bfrag[nt][kq] = *(const s16x8*)&WT[(size_t)(nt * 16 + u) * 1024 + kh + kq * 32];
    }
    __syncthreads();

    // ---- phase D: wave w owns K-slice [w*128, w*128+128) ----
    f32x4 acc[2][4];
    #pragma unroll
    for (int mt = 0; mt < 2; ++mt)
        #pragma unroll
        for (int nt = 0; nt < 4; ++nt)
            acc[mt][nt] = (f32x4){0.f, 0.f, 0.f, 0.f};

    const int kbase = w * 128 + ((l >> 4) << 3);
    #pragma unroll
    for (int kq = 0; kq < 4; ++kq) {
        s16x8 afr[2];
        #pragma unroll
        for (int mt = 0; mt < 2; ++mt) {
            const int row = mt * 16 + (l & 15);
            const int kk  = (kbase + kq * 32) ^ ((row & 7) << 3);
            afr[mt] = *(const s16x8*)&aS[row * 1024 + kk];
        }
        #pragma unroll
        for (int mt = 0; mt < 2; ++mt)
            #pragma unroll
            for (int nt = 0; nt < 4; ++nt)
                acc[mt][nt] = __builtin_amdgcn_mfma_f32_16x16x32_bf16(
                    afr[mt], bfrag[nt][kq], acc[mt][nt], 0, 0, 0);
    }
    __syncthreads();   // aS reads done before pS overwrite

    #pragma unroll
    for (int mt = 0; mt < 2; ++mt)
        #pragma unroll
        for (int nt = 0; nt < 4; ++nt)
            #pragma unroll
            for (int q = 0; q < 4; ++q) {
                const int e = mt * 16 + ((l >> 4) << 2) + q;
                const int u = nt * 16 + (l & 15);
                pS[(w * 32 + e) * 64 + u] = acc[mt][nt][q];
            }
    __syncthreads();

    // ---- reduce 8 K-slices into regs ----
    f32x4 s;
    {
        const int e  = tid >> 4;
        const int u0 = (tid & 15) << 2;
        s = (f32x4){0.f, 0.f, 0.f, 0.f};
        #pragma unroll
        for (int ww = 0; ww < 8; ++ww)
            s += *(const f32x4*)&pS[(ww * 32 + e) * 64 + u0];
    }
    __syncthreads();   // all pS reads done

    // ---- xb -> bf16 swizzled LDS tile [32 rows][64 k] (RS=128B), aliases aS
    unsigned short* xbS = aS;
    {
        const int e  = tid >> 4;
        const int u0 = (tid & 15) << 2;
        uint2 p;
        p.x = cvtpk(s[0], s[1]);
        p.y = cvtpk(s[2], s[3]);
        *(uint2*)((char*)xbS + e * 128 + ((u0 * 2) ^ ((e & 7) << 4))) = p;
    }
    __syncthreads();

    // ---- fused st3 / ts3: waves 0-3 -> y_st quarters, waves 4-7 -> y_ts ----
    const unsigned short* Wsel = (w < 4) ? Wst3 : Wts3;
    unsigned short*       ysel = (w < 4) ? yst : yts;
    const int wmF = w & 3;

    s16x8 awF[2][2];
    load_w<2, 2>(Wsel + (size_t)(wmF * 32) * 64, 64, l, awF);
    f32x4 accF[2][2];
    zacc(accF);
    gemm_pre<2, 2, 2>(awF, (const char*)xbS, 128, 0, l, accF);

    #pragma unroll
    for (int mt = 0; mt < 2; ++mt)
        #pragma unroll
        for (int nf = 0; nf < 2; ++nf) {
            const int row = nf * 16 + fr;
            const int of0 = wmF * 32 + mt * 16 + fq;
            f32x4 v;
            #pragma unroll
            for (int q = 0; q < 4; ++q) v[q] = act_silu(accF[mt][nf][q]);
            store_bf4(&ysel[(size_t)(e0 + row) * 128 + of0], v);
        }
}

// ---------------------------------------------------------------------------
// launch
// ---------------------------------------------------------------------------
extern "C" void kernel_launch(void* const* d_in, const int* in_sizes, int n_in,
                              void* d_out, int out_size, void* d_ws, size_t ws_size,
                              hipStream_t stream)
{
    const float* m_st      = (const float*)d_in[1];
    const float* rbf_h     = (const float*)d_in[2];
    const float* rbf3      = (const float*)d_in[3];
    const float* cbf_rbfW1 = (const float*)d_in[4];
    const float* cbf_sph   = (const float*)d_in[5];
    const float* W_mlp_st  = (const float*)d_in[6];
    const float* W_m_kt    = (const float*)d_in[7];
    const float* W_t_rbf   = (const float*)d_in[8];
    const float* W_down    = (const float*)d_in[9];
    const float* W_bil     = (const float*)d_in[10];
    const float* W_st3     = (const float*)d_in[11];
    const float* W_ts3     = (const float*)d_in[12];
    const float* resb      = (const float*)d_in[13];
    const float* resa      = (const float*)d_in[14];
    const float* W_ae_rbf  = (const float*)d_in[15];
    const float* W_ae_in   = (const float*)d_in[16];
    const float* resat     = (const float*)d_in[17];
    const float* W_asi     = (const float*)d_in[18];
    const float* resm      = (const float*)d_in[19];
    const int*   idx_s     = (const int*)d_in[20];
    const int*   idx_t     = (const int*)d_in[21];
    const int*   idx_swap  = (const int*)d_in[22];
    const int*   id3_kt    = (const int*)d_in[23];

    float* h2 = (float*)d_ws;                               // NA x 128 f32
    unsigned short* yst_b   = (unsigned short*)(h2 + (size_t)NA * 128);
    unsigned short* yts_b   = yst_b + (size_t)EE * 128;
    unsigned short* x_b     = yts_b + (size_t)EE * 128;
    unsigned short* mkt_b   = x_b + (size_t)EE * 128;
    unsigned short* xb_b    = mkt_b + (size_t)EE * 64;      // (unused)
    unsigned short* h_b     = xb_b + (size_t)EE * 64;
    unsigned short* WTbil   = h_b + (size_t)NA * 128;
    unsigned short* WTall   = WTbil + 65536;
    int* cnt   = (int*)(WTall + 352256);
    int* start = cnt + NA;
    int* wrk   = start + NA + 1;
    int* order = wrk + NA;

    float* out_h = (float*)d_out;
    float* out_m = out_h + (size_t)NA * 128;

    const dim3 blk(256);
    const dim3 blk5(512);
    const int gE  = (EE + 127) / 128;   // 938
    const int gN64 = (NA + 63) / 64;    // 157
    constexpr size_t SQ = 128 * 128;

    WTab tab; int off = 0; int oi = 0;
    auto put = [&](const float* s, int K, int N) {
        int o = off; tab.d[oi].src = s; tab.d[oi].K = K; tab.d[oi].N = N;
        tab.d[oi].off = o; ++oi; off += K * N; return o;
    };
    const int o_mlp  = put(W_mlp_st, 128, 128);
    const int o_mktw = put(W_m_kt, 128, 128);
    const int o_down = put(W_down, 128, 64);
    const int o_st3  = put(W_st3, 64, 128);
    const int o_ts3  = put(W_ts3, 64, 128);
    const int o_rb0  = put(resb, 128, 128);
    const int o_rb1  = put(resb + SQ, 128, 128);
    const int o_ra0  = put(resa, 128, 128);
    const int o_ra1  = put(resa + SQ, 128, 128);
    const int o_ra2  = put(resa + 2 * SQ, 128, 128);
    const int o_ra3  = put(resa + 3 * SQ, 128, 128);
    const int o_aein = put(W_ae_in, 128, 128);
    const int o_rat0 = put(resat, 128, 128);
    const int o_rat1 = put(resat + SQ, 128, 128);
    const int o_rat2 = put(resat + 2 * SQ, 128, 128);
    const int o_rat3 = put(resat + 3 * SQ, 128, 128);
    const int o_asi  = put(W_asi, 384, 128);
    const int o_rm0  = put(resm, 128, 128);
    const int o_rm1  = put(resm + SQ, 128, 128);
    const int o_rm2  = put(resm + 2 * SQ, 128, 128);
    const int o_rm3  = put(resm + 3 * SQ, 128, 128);

    hipMemsetAsync(cnt, 0, NA * sizeof(int), stream);
    wconv_k<<<65536 / 256, blk, 0, stream>>>(W_bil, WTbil);
    wconvall_k<<<21, blk, 0, stream>>>(tab, WTall);
    hist_k<<<(EE + 255) / 256, blk, 0, stream>>>(idx_t, cnt);
    scan_k<<<1, blk, 0, stream>>>(cnt, start, wrk);
    place_k<<<(EE + 255) / 256, blk, 0, stream>>>(idx_t, wrk, order);

    front_k<<<gE, blk5, 0, stream>>>(m_st, rbf3, W_t_rbf,
                                     WTall + o_mktw, WTall + o_down, mkt_b);
    bilinear8_k<<<EE / 32, blk5, 0, stream>>>(
        mkt_b, cbf_rbfW1, cbf_sph, id3_kt, WTbil,
        WTall + o_st3, WTall + o_ts3, yst_b, yts_b);
    chain_k<<<gE, blk5, 0, stream>>>(
        m_st, yst_b, yts_b, idx_swap,
        WTall + o_mlp, WTall + o_rb0, WTall + o_rb1,
        WTall + o_ra0, WTall + o_ra1, WTall + o_ra2, WTall + o_ra3,
        x_b);
    segsum_k<<<(NA + 3) / 4, blk, 0, stream>>>(x_b, rbf_h, W_ae_rbf, start, order, h2);
    atom_k<<<gN64, blk5, 0, stream>>>(
        h2, WTall + o_aein,
        WTall + o_rat0, WTall + o_rat1, WTall + o_rat2, WTall + o_rat3,
        out_h, h_b);
    asi_k<<<gE, blk5, 0, stream>>>(
        h_b, x_b, idx_s, idx_t,
        WTall + o_asi,
        WTall + o_rm0, WTall + o_rm1, WTall + o_rm2, WTall + o_rm3,
        out_m);
}